// Round 4
// baseline (481.725 us; speedup 1.0000x reference)
//
#include <hip/hip_runtime.h>
#include <hip/hip_bf16.h>

#define NN 262144
#define DD 256
#define HH 128
#define GG 2048

typedef __attribute__((ext_vector_type(8))) __bf16 bf16x8;
typedef __attribute__((ext_vector_type(4))) float f32x4;

union ABFrag { bf16x8 v; unsigned short u[8]; uint4 i; };

__device__ __forceinline__ unsigned short f2bf(float f) {
    unsigned int u = __float_as_uint(f);
    return (unsigned short)((u + 0x7fffu + ((u >> 16) & 1u)) >> 16);
}
__device__ __forceinline__ float bf2f(unsigned short s) {
    return __uint_as_float(((unsigned int)s) << 16);
}

// ---- kernel 0: prep (W1 -> bf16 W1T) + segment bounds, merged --------------
__global__ void prep_kernel(const float* __restrict__ w1, unsigned short* __restrict__ w1t,
                            const int* __restrict__ batch, int* __restrict__ bnd) {
    int b = blockIdx.x;
    int tid = threadIdx.x;
    if (b < 128) {
        int i = b * 256 + tid;          // 0..32767 over W1T elements
        int n = i >> 8;                  // hidden dim
        int k = i & 255;                 // input dim
        w1t[i] = f2bf(w1[k * HH + n]);
    } else {
        int g = (b - 128) * 256 + tid;   // 0..GG inclusive
        if (g > GG) return;
        int lo = 0, hi = NN;
        while (lo < hi) { int mid = (lo + hi) >> 1; if (batch[mid] < g) lo = mid + 1; else hi = mid; }
        bnd[g] = lo;
    }
}

// ---- kernel 1: fused scores + online softmax + pooling ----------------------
// One block (4 waves) per graph; 64-row chunks; 3 barriers per chunk.
//  stage  : 64 rows x -> LDS bf16, XOR-swizzled (conflict-free)
//  mfma   : wave w holds B-frags for hidden tiles {2w,2w+1} in regs, computes
//           partial scores for ALL 64 rows -> part[4][64]
//  phase B: ALL waves redundantly combine partials + online softmax (e in regs)
//  phase C: weighted accumulate from LDS bf16 (no global re-read)
__global__ __launch_bounds__(256, 4)
void fused_kernel(const float* __restrict__ x,
                  const unsigned short* __restrict__ w1t,
                  const float* __restrict__ b1,
                  const float* __restrict__ w2,
                  const int* __restrict__ bnd,
                  float* __restrict__ out)
{
    __shared__ __align__(16) unsigned short xs[64 * DD];   // 32 KB
    __shared__ float part[4 * 64];                          // 1 KB

    const int g = blockIdx.x;
    const int tid = threadIdx.x;
    const int lane = tid & 63;
    const int wv = tid >> 6;
    const int c = lane & 15;
    const int q = lane >> 4;
    const int blk = lane & 31;               // phase C: column block (8 cols)
    const int g0 = wv * 2 + (lane >> 5);     // phase C: row group 0..7

    const int start = bnd[g];
    const int end = bnd[g + 1];

    // persistent B-frags: this wave's 2 hidden tiles, all 8 K-steps (64 VGPRs)
    ABFrag bfr[2][8];
#pragma unroll
    for (int j = 0; j < 2; ++j)
#pragma unroll
        for (int kk = 0; kk < 8; ++kk)
            bfr[j][kk].i = *(const uint4*)(w1t + (size_t)((2 * wv + j) * 16 + c) * DD + kk * 32 + q * 8);

    float b1v[2], w2v[2];
#pragma unroll
    for (int j = 0; j < 2; ++j) {
        b1v[j] = b1[(2 * wv + j) * 16 + c];
        w2v[j] = w2[(2 * wv + j) * 16 + c];
    }

    float acc[8];                            // my 8 output cols: blk*8..blk*8+7
#pragma unroll
    for (int j = 0; j < 8; ++j) acc[j] = 0.f;
    float m = -3.402823466e38f;              // running max (identical in all waves)
    float l = 0.f;                           // running sum

    for (int base = start; base < end; base += 64) {
        const int n = min(64, end - base);

        // ---- stage: 64 rows -> LDS bf16, swizzled ----
#pragma unroll
        for (int jj = 0; jj < 8; ++jj) {
            int id = jj * 256 + tid;
            int row = id >> 5;               // 0..63
            int bb = id & 31;                // 16B block within row
            ABFrag af;
            if (row < n) {
                const float4* p4 = (const float4*)(x + (size_t)(base + row) * DD + bb * 8);
                float4 f0 = p4[0], f1 = p4[1];
                af.u[0] = f2bf(f0.x); af.u[1] = f2bf(f0.y); af.u[2] = f2bf(f0.z); af.u[3] = f2bf(f0.w);
                af.u[4] = f2bf(f1.x); af.u[5] = f2bf(f1.y); af.u[6] = f2bf(f1.z); af.u[7] = f2bf(f1.w);
            } else {
                af.i = (uint4){0u, 0u, 0u, 0u};
            }
            *(uint4*)&xs[row * DD + ((bb ^ (row & 7)) << 3)] = af.i;
        }
        __syncthreads();

        // ---- mfma: 4 m-tiles x 2 hidden tiles ----
        f32x4 accs[4][2];
#pragma unroll
        for (int mt = 0; mt < 4; ++mt)
#pragma unroll
            for (int j = 0; j < 2; ++j) accs[mt][j] = (f32x4){0.f, 0.f, 0.f, 0.f};

#pragma unroll
        for (int kk = 0; kk < 8; ++kk) {
            ABFrag af[4];
#pragma unroll
            for (int mt = 0; mt < 4; ++mt)
                af[mt].i = *(const uint4*)&xs[(mt * 16 + c) * DD + (((kk * 4 + q) ^ (c & 7)) << 3)];
#pragma unroll
            for (int mt = 0; mt < 4; ++mt)
#pragma unroll
                for (int j = 0; j < 2; ++j)
                    accs[mt][j] = __builtin_amdgcn_mfma_f32_16x16x32_bf16(af[mt].v, bfr[j][kk].v, accs[mt][j], 0, 0, 0);
        }

        // epilogue: +b1, relu, *w2, reduce my 32 hidden dims -> partial scores
#pragma unroll
        for (int mt = 0; mt < 4; ++mt) {
            float s0 = 0.f, s1 = 0.f, s2 = 0.f, s3 = 0.f;
#pragma unroll
            for (int j = 0; j < 2; ++j) {
                float w = w2v[j], bb = b1v[j];
                f32x4 a = accs[mt][j];
                s0 += fmaxf(a.x + bb, 0.f) * w;
                s1 += fmaxf(a.y + bb, 0.f) * w;
                s2 += fmaxf(a.z + bb, 0.f) * w;
                s3 += fmaxf(a.w + bb, 0.f) * w;
            }
#pragma unroll
            for (int off = 1; off < 16; off <<= 1) {
                s0 += __shfl_xor(s0, off);
                s1 += __shfl_xor(s1, off);
                s2 += __shfl_xor(s2, off);
                s3 += __shfl_xor(s3, off);
            }
            if (c == 0) {
                float* o = part + wv * 64 + mt * 16 + q * 4;
                o[0] = s0; o[1] = s1; o[2] = s2; o[3] = s3;
            }
        }
        __syncthreads();

        // ---- phase B: combine partials + online softmax (ALL waves, redundant) ----
        float s = (lane < n)
            ? (part[lane] + part[64 + lane] + part[128 + lane] + part[192 + lane])
            : -3.402823466e38f;
        float cmax = s;
#pragma unroll
        for (int off = 1; off < 64; off <<= 1) cmax = fmaxf(cmax, __shfl_xor(cmax, off));
        float newm = fmaxf(m, cmax);
        float alpha = (m > -1.0e37f) ? __expf(m - newm) : 0.f;
        float e = (lane < n) ? __expf(s - newm) : 0.f;
        float es = e;
#pragma unroll
        for (int off = 1; off < 64; off <<= 1) es += __shfl_xor(es, off);
        l = l * alpha + es;
        m = newm;

        // ---- phase C: rescale + weighted accumulate from LDS bf16 ----
#pragma unroll
        for (int j = 0; j < 8; ++j) acc[j] *= alpha;
#pragma unroll
        for (int i = 0; i < 8; ++i) {
            int row = g0 + 8 * i;
            float w = __shfl(e, row);
            ABFrag xf;
            xf.i = *(const uint4*)&xs[row * DD + ((blk ^ (row & 7)) << 3)];
#pragma unroll
            for (int j = 0; j < 8; ++j) acc[j] = fmaf(w, bf2f(xf.u[j]), acc[j]);
        }
        __syncthreads();   // protect xs & part before next chunk's writes
    }

    // ---- final: cross-group reduction (8 row-groups), divide by l, store ----
    float* arr = (float*)xs;    // 8 groups x 256 cols = 8 KB (xs reads fenced)
    *(float4*)&arr[g0 * 256 + blk * 8]     = (float4){acc[0], acc[1], acc[2], acc[3]};
    *(float4*)&arr[g0 * 256 + blk * 8 + 4] = (float4){acc[4], acc[5], acc[6], acc[7]};
    __syncthreads();
    float inv = (l > 0.f) ? 1.f / l : 0.f;
    float sum = 0.f;
#pragma unroll
    for (int k = 0; k < 8; ++k) sum += arr[k * 256 + tid];
    out[(size_t)g * DD + tid] = sum * inv;
}

extern "C" void kernel_launch(void* const* d_in, const int* in_sizes, int n_in,
                              void* d_out, int out_size, void* d_ws, size_t ws_size,
                              hipStream_t stream) {
    const float* x     = (const float*)d_in[0];
    const int*   batch = (const int*)d_in[1];
    const float* W1    = (const float*)d_in[3];
    const float* b1    = (const float*)d_in[4];
    const float* W2    = (const float*)d_in[5];
    float* out = (float*)d_out;

    char* ws = (char*)d_ws;
    unsigned short* w1t = (unsigned short*)ws;                 // 32768 bf16 (64 KB)
    int*            bnd = (int*)(ws + 65536);                  // GG+1 ints

    prep_kernel<<<128 + (GG + 1 + 255) / 256, 256, 0, stream>>>(W1, w1t, batch, bnd);
    fused_kernel<<<GG, 256, 0, stream>>>(x, w1t, b1, W2, bnd, out);
}

// Round 5
// 384.279 us; speedup vs baseline: 1.2536x; 1.2536x over previous
//
#include <hip/hip_runtime.h>
#include <hip/hip_bf16.h>

#define NN 262144
#define DD 256
#define HH 128
#define GG 2048

typedef __attribute__((ext_vector_type(8))) __bf16 bf16x8;
typedef __attribute__((ext_vector_type(4))) float f32x4;

union ABFrag { bf16x8 v; unsigned short u[8]; uint4 i; };

__device__ __forceinline__ unsigned short f2bf(float f) {
    unsigned int u = __float_as_uint(f);
    return (unsigned short)((u + 0x7fffu + ((u >> 16) & 1u)) >> 16);
}
__device__ __forceinline__ float bf2f(unsigned short s) {
    return __uint_as_float(((unsigned int)s) << 16);
}

// ---- kernel 0: prep (W1 -> bf16 W1T) + segment bounds, merged --------------
__global__ void prep_kernel(const float* __restrict__ w1, unsigned short* __restrict__ w1t,
                            const int* __restrict__ batch, int* __restrict__ bnd) {
    int b = blockIdx.x;
    int tid = threadIdx.x;
    if (b < 128) {
        int i = b * 256 + tid;
        int n = i >> 8;
        int k = i & 255;
        w1t[i] = f2bf(w1[k * HH + n]);
    } else {
        int g = (b - 128) * 256 + tid;
        if (g > GG) return;
        int lo = 0, hi = NN;
        while (lo < hi) { int mid = (lo + hi) >> 1; if (batch[mid] < g) lo = mid + 1; else hi = mid; }
        bnd[g] = lo;
    }
}

// ---- kernel 1: fused scores + online softmax + pooling ----------------------
// One block (4 waves) per graph; 64-row chunks; register-prefetch pipeline:
//   while chunk t is MFMA'd/pooled, chunk t+1's 64 KB of x loads are in
//   flight into 64 prefetch VGPRs (G). Keeps ~128 KB/CU outstanding -> HBM-bound.
// 3 barriers/chunk: B1 xs-writable, B2 xs-ready, B3 part-ready.
__global__ __launch_bounds__(256, 2)
void fused_kernel(const float* __restrict__ x,
                  const unsigned short* __restrict__ w1t,
                  const float* __restrict__ b1,
                  const float* __restrict__ w2,
                  const int* __restrict__ bnd,
                  float* __restrict__ out)
{
    __shared__ __align__(16) unsigned short xs[64 * DD];   // 32 KB
    __shared__ float part[4 * 64];                          // 1 KB

    const int g = blockIdx.x;
    const int tid = threadIdx.x;
    const int lane = tid & 63;
    const int wv = tid >> 6;
    const int c = lane & 15;
    const int q = lane >> 4;
    const int blk = lane & 31;               // phase C: column block (8 cols)
    const int g0 = wv * 2 + (lane >> 5);     // phase C: row group 0..7

    const int start = bnd[g];
    const int end = bnd[g + 1];

    // stage-load geometry for this thread (same for every chunk)
    const int srow = tid >> 5;               // my row within chunk (two per jj step)
    const int sbb  = tid & 31;               // my 16B block within row

    // persistent B-frags: this wave's 2 hidden tiles, all 8 K-steps (64 VGPRs)
    ABFrag bfr[2][8];
#pragma unroll
    for (int j = 0; j < 2; ++j)
#pragma unroll
        for (int kk = 0; kk < 8; ++kk)
            bfr[j][kk].i = *(const uint4*)(w1t + (size_t)((2 * wv + j) * 16 + c) * DD + kk * 32 + q * 8);

    float b1v[2], w2v[2];
#pragma unroll
    for (int j = 0; j < 2; ++j) {
        b1v[j] = b1[(2 * wv + j) * 16 + c];
        w2v[j] = w2[(2 * wv + j) * 16 + c];
    }

    float acc[8];
#pragma unroll
    for (int j = 0; j < 8; ++j) acc[j] = 0.f;
    float m = -3.402823466e38f;
    float l = 0.f;

    // ---- prefetch chunk 0 into G (64 VGPRs) ----
    float4 G[16];
#pragma unroll
    for (int jj = 0; jj < 8; ++jj) {
        int row = srow + jj * 8;
        int r = min(start + row, NN - 1);     // clamp: OOB-safe, zeroed at commit
        const float4* p4 = (const float4*)(x + (size_t)r * DD + sbb * 8);
        G[2 * jj]     = p4[0];
        G[2 * jj + 1] = p4[1];
    }

    for (int base = start; base < end; base += 64) {
        const int n = min(64, end - base);

        __syncthreads();   // B1: previous chunk's xs readers are done

        // ---- commit G -> xs (bf16, swizzled; zero rows >= n) ----
#pragma unroll
        for (int jj = 0; jj < 8; ++jj) {
            int row = srow + jj * 8;
            ABFrag af;
            if (row < n) {
                float4 f0 = G[2 * jj], f1 = G[2 * jj + 1];
                af.u[0] = f2bf(f0.x); af.u[1] = f2bf(f0.y); af.u[2] = f2bf(f0.z); af.u[3] = f2bf(f0.w);
                af.u[4] = f2bf(f1.x); af.u[5] = f2bf(f1.y); af.u[6] = f2bf(f1.z); af.u[7] = f2bf(f1.w);
            } else {
                af.i = (uint4){0u, 0u, 0u, 0u};
            }
            *(uint4*)&xs[row * DD + ((sbb ^ (row & 7)) << 3)] = af.i;
        }
        __syncthreads();   // B2: xs ready

        // ---- issue prefetch for chunk t+1 (in flight during MFMA + pool) ----
        if (base + 64 < end) {
            const int nb = base + 64;
#pragma unroll
            for (int jj = 0; jj < 8; ++jj) {
                int row = srow + jj * 8;
                int r = min(nb + row, NN - 1);
                const float4* p4 = (const float4*)(x + (size_t)r * DD + sbb * 8);
                G[2 * jj]     = p4[0];
                G[2 * jj + 1] = p4[1];
            }
        }

        // ---- mfma: 4 m-tiles x 2 hidden tiles ----
        f32x4 accs[4][2];
#pragma unroll
        for (int mt = 0; mt < 4; ++mt)
#pragma unroll
            for (int j = 0; j < 2; ++j) accs[mt][j] = (f32x4){0.f, 0.f, 0.f, 0.f};

#pragma unroll
        for (int kk = 0; kk < 8; ++kk) {
            ABFrag af[4];
#pragma unroll
            for (int mt = 0; mt < 4; ++mt)
                af[mt].i = *(const uint4*)&xs[(mt * 16 + c) * DD + (((kk * 4 + q) ^ (c & 7)) << 3)];
#pragma unroll
            for (int mt = 0; mt < 4; ++mt)
#pragma unroll
                for (int j = 0; j < 2; ++j)
                    accs[mt][j] = __builtin_amdgcn_mfma_f32_16x16x32_bf16(af[mt].v, bfr[j][kk].v, accs[mt][j], 0, 0, 0);
        }

        // epilogue: +b1, relu, *w2, reduce my 32 hidden dims -> partial scores
#pragma unroll
        for (int mt = 0; mt < 4; ++mt) {
            float s0 = 0.f, s1 = 0.f, s2 = 0.f, s3 = 0.f;
#pragma unroll
            for (int j = 0; j < 2; ++j) {
                float w = w2v[j], bb = b1v[j];
                f32x4 a = accs[mt][j];
                s0 += fmaxf(a.x + bb, 0.f) * w;
                s1 += fmaxf(a.y + bb, 0.f) * w;
                s2 += fmaxf(a.z + bb, 0.f) * w;
                s3 += fmaxf(a.w + bb, 0.f) * w;
            }
#pragma unroll
            for (int off = 1; off < 16; off <<= 1) {
                s0 += __shfl_xor(s0, off);
                s1 += __shfl_xor(s1, off);
                s2 += __shfl_xor(s2, off);
                s3 += __shfl_xor(s3, off);
            }
            if (c == 0) {
                float* o = part + wv * 64 + mt * 16 + q * 4;
                o[0] = s0; o[1] = s1; o[2] = s2; o[3] = s3;
            }
        }
        __syncthreads();   // B3: part ready

        // ---- phase B: combine partials + online softmax (all waves) ----
        float s = (lane < n)
            ? (part[lane] + part[64 + lane] + part[128 + lane] + part[192 + lane])
            : -3.402823466e38f;
        float cmax = s;
#pragma unroll
        for (int off = 1; off < 64; off <<= 1) cmax = fmaxf(cmax, __shfl_xor(cmax, off));
        float newm = fmaxf(m, cmax);
        float alpha = (m > -1.0e37f) ? __expf(m - newm) : 0.f;
        float e = (lane < n) ? __expf(s - newm) : 0.f;
        float es = e;
#pragma unroll
        for (int off = 1; off < 64; off <<= 1) es += __shfl_xor(es, off);
        l = l * alpha + es;
        m = newm;

        // ---- phase C: rescale + weighted accumulate from LDS bf16 ----
#pragma unroll
        for (int j = 0; j < 8; ++j) acc[j] *= alpha;
#pragma unroll
        for (int i = 0; i < 8; ++i) {
            int row = g0 + 8 * i;
            float w = __shfl(e, row);
            ABFrag xf;
            xf.i = *(const uint4*)&xs[row * DD + ((blk ^ (row & 7)) << 3)];
#pragma unroll
            for (int j = 0; j < 8; ++j) acc[j] = fmaf(w, bf2f(xf.u[j]), acc[j]);
        }
    }

    // ---- final: cross-group reduction (8 row-groups), divide by l, store ----
    __syncthreads();            // all phase-C xs reads done
    float* arr = (float*)xs;    // reuse stage buffer: 8 groups x 256 cols = 8 KB
    *(float4*)&arr[g0 * 256 + blk * 8]     = (float4){acc[0], acc[1], acc[2], acc[3]};
    *(float4*)&arr[g0 * 256 + blk * 8 + 4] = (float4){acc[4], acc[5], acc[6], acc[7]};
    __syncthreads();
    float inv = (l > 0.f) ? 1.f / l : 0.f;
    float sum = 0.f;
#pragma unroll
    for (int k = 0; k < 8; ++k) sum += arr[k * 256 + tid];
    out[(size_t)g * DD + tid] = sum * inv;
}

extern "C" void kernel_launch(void* const* d_in, const int* in_sizes, int n_in,
                              void* d_out, int out_size, void* d_ws, size_t ws_size,
                              hipStream_t stream) {
    const float* x     = (const float*)d_in[0];
    const int*   batch = (const int*)d_in[1];
    const float* W1    = (const float*)d_in[3];
    const float* b1    = (const float*)d_in[4];
    const float* W2    = (const float*)d_in[5];
    float* out = (float*)d_out;

    char* ws = (char*)d_ws;
    unsigned short* w1t = (unsigned short*)ws;                 // 32768 bf16 (64 KB)
    int*            bnd = (int*)(ws + 65536);                  // GG+1 ints

    prep_kernel<<<128 + (GG + 1 + 255) / 256, 256, 0, stream>>>(W1, w1t, batch, bnd);
    fused_kernel<<<GG, 256, 0, stream>>>(x, w1t, b1, W2, bnd, out);
}